// Round 2
// baseline (153.520 us; speedup 1.0000x reference)
//
#include <hip/hip_runtime.h>
#include <stdint.h>

typedef __attribute__((ext_vector_type(8))) short short8;
typedef __attribute__((ext_vector_type(16))) float floatx16;
typedef unsigned int u32;
typedef unsigned short u16;

#define TPW 16  // tiles (of 32 points) per wave

// round-to-nearest-even f32->bf16, packed pair (a -> low16, b -> high16)
__device__ __forceinline__ u32 pkrtn(float a, float b) {
  u32 ua = __float_as_uint(a);
  u32 ub = __float_as_uint(b);
  ua += 0x7fffu + ((ua >> 16) & 1u);
  ub += 0x7fffu + ((ub >> 16) & 1u);
  return (ua >> 16) | (ub & 0xffff0000u);
}

__device__ __forceinline__ u16 rtn1(float a) {
  u32 ua = __float_as_uint(a);
  ua += 0x7fffu + ((ua >> 16) & 1u);
  return (u16)(ua >> 16);
}

// channel<->k-slot permutation (involution): swap bits 2 and 3 of low nibble.
// Maps C/D-layout register order onto B-operand k-slots so layer transitions
// are pure in-lane packs; weight columns are gathered through the same map.
__device__ __forceinline__ int sigperm(int k) {
  int r = k & 15;
  int s = (r & 3) | ((r & 4) << 1) | ((r & 8) >> 1);
  return (k & ~15) | s;
}

// pack 8 consecutive accumulator regs (base=0 or 8) into one B-frag
__device__ __forceinline__ short8 packhalf(const floatx16 a, int base, bool relu) {
  union { u32 u[4]; short8 v; } r;
#pragma unroll
  for (int i = 0; i < 4; ++i) {
    float p = a[base + 2 * i];
    float q = a[base + 2 * i + 1];
    if (relu) { p = fmaxf(p, 0.0f); q = fmaxf(q, 0.0f); }
    r.u[i] = pkrtn(p, q);
  }
  return r.v;
}

#define MFMA(A, B, C) __builtin_amdgcn_mfma_f32_32x32x16_bf16(A, B, C, 0, 0, 0)

// LDS offsets (bf16 elements) for staged (converted) weights
#define OFF_S0 0
#define OFF_S1 192
#define OFF_S2 4288
#define OFF_C0 5312
#define OFF_C1 6464
#define OFF_C2 10560
#define OFF_C3 14656
#define WTOT   14848

__global__ __launch_bounds__(256, 2) void nerf_fused(
    const float* __restrict__ x,
    const float* __restrict__ w_s0, const float* __restrict__ w_s1,
    const float* __restrict__ w_s2, const float* __restrict__ w_c0,
    const float* __restrict__ w_c1, const float* __restrict__ w_c2,
    const float* __restrict__ w_c3,
    float* __restrict__ out, int npts) {
  __shared__ u16 wl[WTOT];

  // ---- stage weights fp32 -> bf16 into LDS, once per block ----
  {
    const float* srcs[7] = {w_s0, w_s1, w_s2, w_c0, w_c1, w_c2, w_c3};
    const int sz[7]  = {192, 4096, 1024, 1152, 4096, 4096, 192};
    const int off[7] = {OFF_S0, OFF_S1, OFF_S2, OFF_C0, OFF_C1, OFF_C2, OFF_C3};
#pragma unroll
    for (int a = 0; a < 7; ++a) {
      const float* s = srcs[a];
      u16* d = &wl[off[a]];
      for (int i = threadIdx.x; i < sz[a]; i += 256) d[i] = rtn1(s[i]);
    }
  }
  __syncthreads();

  const int lane = threadIdx.x & 63;
  const int wid = threadIdx.x >> 6;
  const int m = lane & 31;   // A-row / B-col (point) index within tile
  const int hi = lane >> 5;  // half-wave -> k-block
  const int kb = hi << 3;

  // ---- gather weight fragments into registers (A-operand layout) ----
  short8 a_s0[2], a_s1[2][4], a_s2[4], a_c0[2][2], a_c1[2][4], a_c2[2][4], a_c3[4];

  // s0: 64x3, K padded to 16, natural cols (x is packed at k=0..2)
#pragma unroll
  for (int rt = 0; rt < 2; ++rt) {
    const int row = rt * 32 + m;
    union { u16 e[8]; short8 v; } u;
#pragma unroll
    for (int j = 0; j < 8; ++j) {
      const int k = kb + j;
      u16 val = wl[OFF_S0 + row * 3 + ((k < 3) ? k : 0)];
      u.e[j] = (k < 3) ? val : (u16)0;
    }
    a_s0[rt] = u.v;
  }

  // 64x64 layers: sigma-permuted columns
  auto gather64 = [&](int base, short8(*dst)[4]) {
#pragma unroll
    for (int rt = 0; rt < 2; ++rt) {
      const int row = rt * 32 + m;
#pragma unroll
      for (int ks = 0; ks < 4; ++ks) {
        union { u16 e[8]; short8 v; } u;
#pragma unroll
        for (int j = 0; j < 8; ++j)
          u.e[j] = wl[base + row * 64 + sigperm(ks * 16 + kb + j)];
        dst[rt][ks] = u.v;
      }
    }
  };
  gather64(OFF_S1, a_s1);
  gather64(OFF_C1, a_c1);
  gather64(OFF_C2, a_c2);

  // s2: 16x64 (rows 16..31 zero)
#pragma unroll
  for (int ks = 0; ks < 4; ++ks) {
    const int row = (m < 16) ? m : 0;
    union { u16 e[8]; short8 v; } u;
#pragma unroll
    for (int j = 0; j < 8; ++j) {
      u16 val = wl[OFF_S2 + row * 64 + sigperm(ks * 16 + kb + j)];
      u.e[j] = (m < 16) ? val : (u16)0;
    }
    a_s2[ks] = u.v;
  }

  // c0: 64x18. k-slots 0..15 = s2 output (sigma-permuted; ch0=sigma gets zero
  // weight; s2 ch c>=1 is geo_{c-1} = cw0 col c+2); 2nd MFMA slots 0..2 = views.
#pragma unroll
  for (int rt = 0; rt < 2; ++rt) {
    const int row = rt * 32 + m;
#pragma unroll
    for (int ks = 0; ks < 2; ++ks) {
      union { u16 e[8]; short8 v; } u;
#pragma unroll
      for (int j = 0; j < 8; ++j) {
        if (ks == 0) {
          const int c = sigperm(kb + j);
          u16 val = wl[OFF_C0 + row * 18 + (c + 2)];
          u.e[j] = (c == 0) ? (u16)0 : val;
        } else {
          const int kk = kb + j;
          u16 val = wl[OFF_C0 + row * 18 + ((kk < 3) ? kk : 0)];
          u.e[j] = (kk < 3) ? val : (u16)0;
        }
      }
      a_c0[rt][ks] = u.v;
    }
  }

  // c3: 3x64 (rows 3..31 zero)
#pragma unroll
  for (int ks = 0; ks < 4; ++ks) {
    const int row = (m < 3) ? m : 0;
    union { u16 e[8]; short8 v; } u;
#pragma unroll
    for (int j = 0; j < 8; ++j) {
      u16 val = wl[OFF_C3 + row * 64 + sigperm(ks * 16 + kb + j)];
      u.e[j] = (m < 3) ? val : (u16)0;
    }
    a_c3[ks] = u.v;
  }

  // ---- main loop: 32 points per tile, whole network in registers ----
  const int ntiles = npts >> 5;
  const int wgid = blockIdx.x * 4 + wid;
  const floatx16 z = (floatx16)0.0f;

  for (int t = 0; t < TPW; ++t) {
    const int tile = wgid * TPW + t;
    if (tile >= ntiles) break;
    const int pt = (tile << 5) | m;

    // x row: 6 fp32 [p0 p1 p2 v0 v1 v2], 24B, 8B-aligned
    const float2* xp = (const float2*)(x + (size_t)pt * 6);
    const float2 f0 = xp[0], f1 = xp[1], f2 = xp[2];

    union { u32 u[4]; short8 v; } bx, bv;
    bx.u[0] = hi ? 0u : pkrtn(f0.x, f0.y);   // (p0,p1) at k0,k1
    bx.u[1] = hi ? 0u : pkrtn(f1.x, 0.0f);   // (p2, 0)
    bx.u[2] = 0u; bx.u[3] = 0u;
    bv.u[0] = hi ? 0u : pkrtn(f1.y, f2.x);   // (v0,v1)
    bv.u[1] = hi ? 0u : pkrtn(f2.y, 0.0f);   // (v2, 0)
    bv.u[2] = 0u; bv.u[3] = 0u;

    floatx16 h0, h1;

    // sigma L0 (K=3 padded)
    h0 = MFMA(a_s0[0], bx.v, z);
    h1 = MFMA(a_s0[1], bx.v, z);
    short8 b0 = packhalf(h0, 0, true), b1 = packhalf(h0, 8, true);
    short8 b2 = packhalf(h1, 0, true), b3 = packhalf(h1, 8, true);

    // sigma L1 (64->64)
    h0 = MFMA(a_s1[0][0], b0, z);  h1 = MFMA(a_s1[1][0], b0, z);
    h0 = MFMA(a_s1[0][1], b1, h0); h1 = MFMA(a_s1[1][1], b1, h1);
    h0 = MFMA(a_s1[0][2], b2, h0); h1 = MFMA(a_s1[1][2], b2, h1);
    h0 = MFMA(a_s1[0][3], b3, h0); h1 = MFMA(a_s1[1][3], b3, h1);
    b0 = packhalf(h0, 0, true); b1 = packhalf(h0, 8, true);
    b2 = packhalf(h1, 0, true); b3 = packhalf(h1, 8, true);

    // sigma L2 (64->16, NO relu)
    floatx16 hs;
    hs = MFMA(a_s2[0], b0, z);
    hs = MFMA(a_s2[1], b1, hs);
    hs = MFMA(a_s2[2], b2, hs);
    hs = MFMA(a_s2[3], b3, hs);
    const float sigma = hs[0];                 // row 0 (lanes<32) = sigma
    const short8 bs2 = packhalf(hs, 0, false); // ch0..15 (incl sigma, wt=0)

    // color L0 (19->64: s2 slots + views)
    h0 = MFMA(a_c0[0][0], bs2, z);   h1 = MFMA(a_c0[1][0], bs2, z);
    h0 = MFMA(a_c0[0][1], bv.v, h0); h1 = MFMA(a_c0[1][1], bv.v, h1);
    b0 = packhalf(h0, 0, true); b1 = packhalf(h0, 8, true);
    b2 = packhalf(h1, 0, true); b3 = packhalf(h1, 8, true);

    // color L1
    h0 = MFMA(a_c1[0][0], b0, z);  h1 = MFMA(a_c1[1][0], b0, z);
    h0 = MFMA(a_c1[0][1], b1, h0); h1 = MFMA(a_c1[1][1], b1, h1);
    h0 = MFMA(a_c1[0][2], b2, h0); h1 = MFMA(a_c1[1][2], b2, h1);
    h0 = MFMA(a_c1[0][3], b3, h0); h1 = MFMA(a_c1[1][3], b3, h1);
    b0 = packhalf(h0, 0, true); b1 = packhalf(h0, 8, true);
    b2 = packhalf(h1, 0, true); b3 = packhalf(h1, 8, true);

    // color L2
    h0 = MFMA(a_c2[0][0], b0, z);  h1 = MFMA(a_c2[1][0], b0, z);
    h0 = MFMA(a_c2[0][1], b1, h0); h1 = MFMA(a_c2[1][1], b1, h1);
    h0 = MFMA(a_c2[0][2], b2, h0); h1 = MFMA(a_c2[1][2], b2, h1);
    h0 = MFMA(a_c2[0][3], b3, h0); h1 = MFMA(a_c2[1][3], b3, h1);
    b0 = packhalf(h0, 0, true); b1 = packhalf(h0, 8, true);
    b2 = packhalf(h1, 0, true); b3 = packhalf(h1, 8, true);

    // color L3 (64->3, NO relu)
    floatx16 hc;
    hc = MFMA(a_c3[0], b0, z);
    hc = MFMA(a_c3[1], b1, hc);
    hc = MFMA(a_c3[2], b2, hc);
    hc = MFMA(a_c3[3], b3, hc);

    // out[pt] = (color0, color1, color2, sigma) fp32 — rows 0..2 live in
    // regs 0..2 of lanes<32; 16B per point, coalesced dwordx4.
    if (lane < 32) {
      float4 o;
      o.x = hc[0]; o.y = hc[1]; o.z = hc[2]; o.w = sigma;
      *(float4*)(out + (size_t)pt * 4) = o;
    }
  }
}

extern "C" void kernel_launch(void* const* d_in, const int* in_sizes, int n_in,
                              void* d_out, int out_size, void* d_ws, size_t ws_size,
                              hipStream_t stream) {
  const float* x = (const float*)d_in[0];
  const float* sw0 = (const float*)d_in[1];
  const float* sw1 = (const float*)d_in[2];
  const float* sw2 = (const float*)d_in[3];
  const float* cw0 = (const float*)d_in[4];
  const float* cw1 = (const float*)d_in[5];
  const float* cw2 = (const float*)d_in[6];
  const float* cw3 = (const float*)d_in[7];
  float* out = (float*)d_out;

  const int npts = in_sizes[0] / 6;         // 1048576
  const int ntiles = npts >> 5;             // 32768
  const int blocks = (ntiles + 4 * TPW - 1) / (4 * TPW);  // 512

  nerf_fused<<<blocks, 256, 0, stream>>>(x, sw0, sw1, sw2, cw0, cw1, cw2, cw3,
                                         out, npts);
}

// Round 3
// 144.708 us; speedup vs baseline: 1.0609x; 1.0609x over previous
//
#include <hip/hip_runtime.h>
#include <stdint.h>

typedef __attribute__((ext_vector_type(8))) short short8;
typedef __attribute__((ext_vector_type(16))) float floatx16;
typedef unsigned int u32;
typedef unsigned short u16;

#define TPW 16  // tiles (of 32 points) per wave

// round-to-nearest-even f32->bf16 pair pack: result = (hi16(b)<<16)|hi16(a).
// v_bfe + v_add3 per value, one v_perm_b32 merge => ~5 VALU vs ~8 for shift/or.
__device__ __forceinline__ u32 pkrtn(float a, float b) {
  u32 ua = __float_as_uint(a);
  u32 ub = __float_as_uint(b);
  ua += 0x7fffu + ((ua >> 16) & 1u);
  ub += 0x7fffu + ((ub >> 16) & 1u);
  return __builtin_amdgcn_perm(ub, ua, 0x07060302u);  // [ua.b2 ua.b3 ub.b2 ub.b3]
}

__device__ __forceinline__ u16 rtn1(float a) {
  u32 ua = __float_as_uint(a);
  ua += 0x7fffu + ((ua >> 16) & 1u);
  return (u16)(ua >> 16);
}

// channel<->k-slot permutation (involution): swap bits 2 and 3 of low nibble.
// Maps C/D-layout register order onto B-operand k-slots so layer transitions
// are pure in-lane packs; weight columns are gathered through the same map.
// (Algebra HW-verified: R1 passed absmax 4.8e-3.)
__device__ __forceinline__ int sigperm(int k) {
  int r = k & 15;
  int s = (r & 3) | ((r & 4) << 1) | ((r & 8) >> 1);
  return (k & ~15) | s;
}

// pack 8 consecutive accumulator regs (base=0 or 8) into one B-frag
__device__ __forceinline__ short8 packhalf(const floatx16 a, int base, bool relu) {
  union { u32 u[4]; short8 v; } r;
#pragma unroll
  for (int i = 0; i < 4; ++i) {
    float p = a[base + 2 * i];
    float q = a[base + 2 * i + 1];
    if (relu) { p = fmaxf(p, 0.0f); q = fmaxf(q, 0.0f); }
    r.u[i] = pkrtn(p, q);
  }
  return r.v;
}

#define MFMA(A, B, C) __builtin_amdgcn_mfma_f32_32x32x16_bf16(A, B, C, 0, 0, 0)

// Frag-major LDS: 38 frags x 64 lanes x 16B. Frag ids:
//  0..1  s0[rt]          2..9  s1[rt*4+ks]    10..13 s2[ks]
// 14..17 c0[rt*2+ks]    18..25 c1[rt*4+ks]    26..33 c2[rt*4+ks]   34..37 c3[ks]
#define NFRAG 38

__global__ __launch_bounds__(256, 2) void nerf_fused(
    const float* __restrict__ x,
    const float* __restrict__ w_s0, const float* __restrict__ w_s1,
    const float* __restrict__ w_s2, const float* __restrict__ w_c0,
    const float* __restrict__ w_c1, const float* __restrict__ w_c2,
    const float* __restrict__ w_c3,
    float* __restrict__ out, int npts) {
  __shared__ __align__(16) u16 wl[NFRAG * 512];  // 38912 B

  const int lane = threadIdx.x & 63;
  const int wid = threadIdx.x >> 6;
  const int m = lane & 31;   // A-row / B-col (point) index within tile
  const int hi = lane >> 5;  // half-wave -> k-block
  const int kb = hi << 3;

  // ---- prologue: build fragments straight from global, store frag-major ----
  // wave handles frag f = wid + 4k  -> f wave-uniform, l = lane. ~10 iters.
  for (int f = wid; f < NFRAG; f += 4) {
    union { u16 e[8]; uint4 q; } u;
    if (f < 2) {                         // s0: 64x3, K padded to 16
      const int row = f * 32 + m;
#pragma unroll
      for (int j = 0; j < 8; ++j) {
        const int k = kb + j;
        u.e[j] = (k < 3) ? rtn1(w_s0[row * 3 + k]) : (u16)0;
      }
    } else if (f < 10) {                 // s1: 64x64
      const int g = f - 2, rt = g >> 2, ks = g & 3;
      const int row = rt * 32 + m;
#pragma unroll
      for (int j = 0; j < 8; ++j)
        u.e[j] = rtn1(w_s1[row * 64 + sigperm(ks * 16 + kb + j)]);
    } else if (f < 14) {                 // s2: 16x64 (rows 16..31 zero)
      const int ks = f - 10;
      const int row = (m < 16) ? m : 0;
#pragma unroll
      for (int j = 0; j < 8; ++j) {
        u16 v = rtn1(w_s2[row * 64 + sigperm(ks * 16 + kb + j)]);
        u.e[j] = (m < 16) ? v : (u16)0;
      }
    } else if (f < 18) {                 // c0: 64x18 (geo slots + view slots)
      const int g = f - 14, rt = g >> 1, ks = g & 1;
      const int row = rt * 32 + m;
#pragma unroll
      for (int j = 0; j < 8; ++j) {
        if (ks == 0) {
          const int c = sigperm(kb + j);   // s2-output channel in this k-slot
          u16 v = rtn1(w_c0[row * 18 + (c + 2)]);
          u.e[j] = (c == 0) ? (u16)0 : v;  // ch0 = sigma -> weight 0
        } else {
          const int kk = kb + j;           // views at k=0..2 of 2nd MFMA
          u16 v = rtn1(w_c0[row * 18 + kk]);
          u.e[j] = (kk < 3) ? v : (u16)0;
        }
      }
    } else if (f < 26) {                 // c1: 64x64
      const int g = f - 18, rt = g >> 2, ks = g & 3;
      const int row = rt * 32 + m;
#pragma unroll
      for (int j = 0; j < 8; ++j)
        u.e[j] = rtn1(w_c1[row * 64 + sigperm(ks * 16 + kb + j)]);
    } else if (f < 34) {                 // c2: 64x64
      const int g = f - 26, rt = g >> 2, ks = g & 3;
      const int row = rt * 32 + m;
#pragma unroll
      for (int j = 0; j < 8; ++j)
        u.e[j] = rtn1(w_c2[row * 64 + sigperm(ks * 16 + kb + j)]);
    } else {                             // c3: 3x64 (rows 3..31 zero)
      const int ks = f - 34;
      const int row = (m < 3) ? m : 0;
#pragma unroll
      for (int j = 0; j < 8; ++j) {
        u16 v = rtn1(w_c3[row * 64 + sigperm(ks * 16 + kb + j)]);
        u.e[j] = (m < 3) ? v : (u16)0;
      }
    }
    *(uint4*)(wl + f * 512 + lane * 8) = u.q;
  }
  __syncthreads();

  // in-loop fragment load: one dense conflict-free ds_read_b128
#define LD(F) (*(const short8*)(wl + (F) * 512 + lane * 8))

  // ---- main loop: 32 points per tile, net layers via MFMA ----
  const int ntiles = npts >> 5;
  const int wgid = blockIdx.x * 4 + wid;
  const floatx16 z = (floatx16)0.0f;

  for (int t = 0; t < TPW; ++t) {
    const int tile = wgid * TPW + t;
    if (tile >= ntiles) break;
    const int pt = (tile << 5) | m;

    // x row: 6 fp32 [p0 p1 p2 v0 v1 v2], 24B, 8B-aligned
    const float2* xp = (const float2*)(x + (size_t)pt * 6);
    const float2 f0 = xp[0], f1 = xp[1], f2 = xp[2];

    union { u32 u[4]; short8 v; } bx, bv;
    bx.u[0] = hi ? 0u : pkrtn(f0.x, f0.y);   // (p0,p1) at k0,k1
    bx.u[1] = hi ? 0u : pkrtn(f1.x, 0.0f);   // (p2, 0)
    bx.u[2] = 0u; bx.u[3] = 0u;
    bv.u[0] = hi ? 0u : pkrtn(f1.y, f2.x);   // (v0,v1)
    bv.u[1] = hi ? 0u : pkrtn(f2.y, 0.0f);   // (v2, 0)
    bv.u[2] = 0u; bv.u[3] = 0u;

    floatx16 h0, h1;

    // sigma L0 (K=3 padded)
    h0 = MFMA(LD(0), bx.v, z);
    h1 = MFMA(LD(1), bx.v, z);
    short8 b0 = packhalf(h0, 0, true), b1 = packhalf(h0, 8, true);
    short8 b2 = packhalf(h1, 0, true), b3 = packhalf(h1, 8, true);

    // sigma L1 (64->64)
    h0 = MFMA(LD(2), b0, z);  h1 = MFMA(LD(6), b0, z);
    h0 = MFMA(LD(3), b1, h0); h1 = MFMA(LD(7), b1, h1);
    h0 = MFMA(LD(4), b2, h0); h1 = MFMA(LD(8), b2, h1);
    h0 = MFMA(LD(5), b3, h0); h1 = MFMA(LD(9), b3, h1);
    b0 = packhalf(h0, 0, true); b1 = packhalf(h0, 8, true);
    b2 = packhalf(h1, 0, true); b3 = packhalf(h1, 8, true);

    // sigma L2 (64->16, NO relu)
    floatx16 hs;
    hs = MFMA(LD(10), b0, z);
    hs = MFMA(LD(11), b1, hs);
    hs = MFMA(LD(12), b2, hs);
    hs = MFMA(LD(13), b3, hs);
    const float sigma = hs[0];                 // row 0 (lanes<32) = sigma
    const short8 bs2 = packhalf(hs, 0, false); // ch0..15 (incl sigma, wt=0)

    // color L0 (19->64: s2 slots + views)
    h0 = MFMA(LD(14), bs2, z);   h1 = MFMA(LD(16), bs2, z);
    h0 = MFMA(LD(15), bv.v, h0); h1 = MFMA(LD(17), bv.v, h1);
    b0 = packhalf(h0, 0, true); b1 = packhalf(h0, 8, true);
    b2 = packhalf(h1, 0, true); b3 = packhalf(h1, 8, true);

    // color L1
    h0 = MFMA(LD(18), b0, z);  h1 = MFMA(LD(22), b0, z);
    h0 = MFMA(LD(19), b1, h0); h1 = MFMA(LD(23), b1, h1);
    h0 = MFMA(LD(20), b2, h0); h1 = MFMA(LD(24), b2, h1);
    h0 = MFMA(LD(21), b3, h0); h1 = MFMA(LD(25), b3, h1);
    b0 = packhalf(h0, 0, true); b1 = packhalf(h0, 8, true);
    b2 = packhalf(h1, 0, true); b3 = packhalf(h1, 8, true);

    // color L2
    h0 = MFMA(LD(26), b0, z);  h1 = MFMA(LD(30), b0, z);
    h0 = MFMA(LD(27), b1, h0); h1 = MFMA(LD(31), b1, h1);
    h0 = MFMA(LD(28), b2, h0); h1 = MFMA(LD(32), b2, h1);
    h0 = MFMA(LD(29), b3, h0); h1 = MFMA(LD(33), b3, h1);
    b0 = packhalf(h0, 0, true); b1 = packhalf(h0, 8, true);
    b2 = packhalf(h1, 0, true); b3 = packhalf(h1, 8, true);

    // color L3 (64->3, NO relu)
    floatx16 hc;
    hc = MFMA(LD(34), b0, z);
    hc = MFMA(LD(35), b1, hc);
    hc = MFMA(LD(36), b2, hc);
    hc = MFMA(LD(37), b3, hc);

    // out[pt] = (color0, color1, color2, sigma) fp32; rows 0..2 are regs 0..2
    // of lanes<32; 16B/point coalesced dwordx4.
    if (lane < 32) {
      float4 o;
      o.x = hc[0]; o.y = hc[1]; o.z = hc[2]; o.w = sigma;
      *(float4*)(out + (size_t)pt * 4) = o;
    }
  }
#undef LD
}

extern "C" void kernel_launch(void* const* d_in, const int* in_sizes, int n_in,
                              void* d_out, int out_size, void* d_ws, size_t ws_size,
                              hipStream_t stream) {
  const float* x = (const float*)d_in[0];
  const float* sw0 = (const float*)d_in[1];
  const float* sw1 = (const float*)d_in[2];
  const float* sw2 = (const float*)d_in[3];
  const float* cw0 = (const float*)d_in[4];
  const float* cw1 = (const float*)d_in[5];
  const float* cw2 = (const float*)d_in[6];
  const float* cw3 = (const float*)d_in[7];
  float* out = (float*)d_out;

  const int npts = in_sizes[0] / 6;         // 1048576
  const int ntiles = npts >> 5;             // 32768
  const int blocks = (ntiles + 4 * TPW - 1) / (4 * TPW);  // 512

  nerf_fused<<<blocks, 256, 0, stream>>>(x, sw0, sw1, sw2, cw0, cw1, cw2, cw3,
                                         out, npts);
}

// Round 4
// 143.411 us; speedup vs baseline: 1.0705x; 1.0090x over previous
//
#include <hip/hip_runtime.h>
#include <stdint.h>

typedef __attribute__((ext_vector_type(8))) short short8;
typedef __attribute__((ext_vector_type(16))) float floatx16;
typedef unsigned int u32;
typedef unsigned short u16;

#define TPW 8  // tiles (of 32 points) per wave -> 1024 blocks = 4 blocks/CU

#if defined(__has_builtin)
#if __has_builtin(__builtin_amdgcn_cvt_pk_bf16_f32)
#define HAVE_CVT_PK_BF16 1
#endif
#endif

#ifdef HAVE_CVT_PK_BF16
typedef __attribute__((ext_vector_type(2))) __bf16 bf16x2;
#endif

// f32 pair -> packed bf16 (a -> low16, b -> high16), round-to-nearest-even
__device__ __forceinline__ u32 pkrtn(float a, float b) {
#ifdef HAVE_CVT_PK_BF16
  union { bf16x2 v; u32 u; } c;
  c.v = __builtin_amdgcn_cvt_pk_bf16_f32(a, b);  // lo=a, hi=b, RNE
  return c.u;
#else
  u32 ua = __float_as_uint(a);
  u32 ub = __float_as_uint(b);
  ua += 0x7fffu + ((ua >> 16) & 1u);
  ub += 0x7fffu + ((ub >> 16) & 1u);
  return __builtin_amdgcn_perm(ub, ua, 0x07060302u);
#endif
}

__device__ __forceinline__ u16 rtn1(float a) {
  u32 ua = __float_as_uint(a);
  ua += 0x7fffu + ((ua >> 16) & 1u);
  return (u16)(ua >> 16);
}

// channel<->k-slot permutation (involution): swap bits 2 and 3 of low nibble.
// Maps C/D-layout register order onto B-operand k-slots so layer transitions
// are pure in-lane packs; weight columns are gathered through the same map.
// (Algebra HW-verified: R1/R3 passed, absmax 4.8e-3.)
__device__ __forceinline__ int sigperm(int k) {
  int r = k & 15;
  int s = (r & 3) | ((r & 4) << 1) | ((r & 8) >> 1);
  return (k & ~15) | s;
}

// pack 8 consecutive accumulator regs (base=0 or 8) into one B-frag
__device__ __forceinline__ short8 packhalf(const floatx16 a, int base, bool relu) {
  union { u32 u[4]; short8 v; } r;
#pragma unroll
  for (int i = 0; i < 4; ++i) {
    float p = a[base + 2 * i];
    float q = a[base + 2 * i + 1];
    if (relu) { p = fmaxf(p, 0.0f); q = fmaxf(q, 0.0f); }
    r.u[i] = pkrtn(p, q);
  }
  return r.v;
}

#define MFMA(A, B, C) __builtin_amdgcn_mfma_f32_32x32x16_bf16(A, B, C, 0, 0, 0)

// Frag-major LDS: 38 frags x 64 lanes x 16B. Frag ids:
//  0..1  s0[rt]          2..9  s1[rt*4+ks]    10..13 s2[ks]
// 14..17 c0[rt*2+ks]    18..25 c1[rt*4+ks]    26..33 c2[rt*4+ks]   34..37 c3[ks]
#define NFRAG 38

__global__ __launch_bounds__(256, 4) void nerf_fused(
    const float* __restrict__ x,
    const float* __restrict__ w_s0, const float* __restrict__ w_s1,
    const float* __restrict__ w_s2, const float* __restrict__ w_c0,
    const float* __restrict__ w_c1, const float* __restrict__ w_c2,
    const float* __restrict__ w_c3,
    float* __restrict__ out, int npts) {
  __shared__ __align__(16) u16 wl[NFRAG * 512];  // 38912 B -> 4 blocks/CU

  const int lane = threadIdx.x & 63;
  const int wid = threadIdx.x >> 6;
  const int m = lane & 31;   // A-row / B-col (point) index within tile
  const int hi = lane >> 5;  // half-wave -> k-block
  const int kb = hi << 3;

  // ---- prologue: build fragments straight from global, store frag-major ----
  for (int f = wid; f < NFRAG; f += 4) {
    union { u16 e[8]; uint4 q; } u;
    if (f < 2) {                         // s0: 64x3, K padded to 16
      const int row = f * 32 + m;
#pragma unroll
      for (int j = 0; j < 8; ++j) {
        const int k = kb + j;
        u.e[j] = (k < 3) ? rtn1(w_s0[row * 3 + k]) : (u16)0;
      }
    } else if (f < 10) {                 // s1: 64x64
      const int g = f - 2, rt = g >> 2, ks = g & 3;
      const int row = rt * 32 + m;
#pragma unroll
      for (int j = 0; j < 8; ++j)
        u.e[j] = rtn1(w_s1[row * 64 + sigperm(ks * 16 + kb + j)]);
    } else if (f < 14) {                 // s2: 16x64 (rows 16..31 zero)
      const int ks = f - 10;
      const int row = (m < 16) ? m : 0;
#pragma unroll
      for (int j = 0; j < 8; ++j) {
        u16 v = rtn1(w_s2[row * 64 + sigperm(ks * 16 + kb + j)]);
        u.e[j] = (m < 16) ? v : (u16)0;
      }
    } else if (f < 18) {                 // c0: 64x18 (geo slots + view slots)
      const int g = f - 14, rt = g >> 1, ks = g & 1;
      const int row = rt * 32 + m;
#pragma unroll
      for (int j = 0; j < 8; ++j) {
        if (ks == 0) {
          const int c = sigperm(kb + j);   // s2-output channel in this k-slot
          u16 v = rtn1(w_c0[row * 18 + (c + 2)]);
          u.e[j] = (c == 0) ? (u16)0 : v;  // ch0 = sigma -> weight 0
        } else {
          const int kk = kb + j;           // views at k=0..2 of 2nd MFMA
          u16 v = rtn1(w_c0[row * 18 + kk]);
          u.e[j] = (kk < 3) ? v : (u16)0;
        }
      }
    } else if (f < 26) {                 // c1: 64x64
      const int g = f - 18, rt = g >> 2, ks = g & 3;
      const int row = rt * 32 + m;
#pragma unroll
      for (int j = 0; j < 8; ++j)
        u.e[j] = rtn1(w_c1[row * 64 + sigperm(ks * 16 + kb + j)]);
    } else if (f < 34) {                 // c2: 64x64
      const int g = f - 26, rt = g >> 2, ks = g & 3;
      const int row = rt * 32 + m;
#pragma unroll
      for (int j = 0; j < 8; ++j)
        u.e[j] = rtn1(w_c2[row * 64 + sigperm(ks * 16 + kb + j)]);
    } else {                             // c3: 3x64 (rows 3..31 zero)
      const int ks = f - 34;
      const int row = (m < 3) ? m : 0;
#pragma unroll
      for (int j = 0; j < 8; ++j) {
        u16 v = rtn1(w_c3[row * 64 + sigperm(ks * 16 + kb + j)]);
        u.e[j] = (m < 3) ? v : (u16)0;
      }
    }
    *(uint4*)(wl + f * 512 + lane * 8) = u.q;
  }
  __syncthreads();

  // in-loop fragment load: one dense conflict-free ds_read_b128
#define LD(F) (*(const short8*)(wl + (F) * 512 + lane * 8))

  // ---- main loop: 32 points per tile, net layers via MFMA ----
  const int ntiles = npts >> 5;
  const int wgid = blockIdx.x * 4 + wid;
  const floatx16 z = (floatx16)0.0f;

  for (int t = 0; t < TPW; ++t) {
    const int tile = wgid * TPW + t;
    if (tile >= ntiles) break;
    const int pt = (tile << 5) | m;

    // x row: 6 fp32 [p0 p1 p2 v0 v1 v2], 24B, 8B-aligned
    const float2* xp = (const float2*)(x + (size_t)pt * 6);
    const float2 f0 = xp[0], f1 = xp[1], f2 = xp[2];

    union { u32 u[4]; short8 v; } bx, bv;
    bx.u[0] = hi ? 0u : pkrtn(f0.x, f0.y);   // (p0,p1) at k0,k1
    bx.u[1] = hi ? 0u : pkrtn(f1.x, 0.0f);   // (p2, 0)
    bx.u[2] = 0u; bx.u[3] = 0u;
    bv.u[0] = hi ? 0u : pkrtn(f1.y, f2.x);   // (v0,v1)
    bv.u[1] = hi ? 0u : pkrtn(f2.y, 0.0f);   // (v2, 0)
    bv.u[2] = 0u; bv.u[3] = 0u;

    floatx16 h0, h1;

    // sigma L0 (K=3 padded)
    h0 = MFMA(LD(0), bx.v, z);
    h1 = MFMA(LD(1), bx.v, z);
    short8 b0 = packhalf(h0, 0, true), b1 = packhalf(h0, 8, true);
    short8 b2 = packhalf(h1, 0, true), b3 = packhalf(h1, 8, true);

    // sigma L1 (64->64)
    h0 = MFMA(LD(2), b0, z);  h1 = MFMA(LD(6), b0, z);
    h0 = MFMA(LD(3), b1, h0); h1 = MFMA(LD(7), b1, h1);
    h0 = MFMA(LD(4), b2, h0); h1 = MFMA(LD(8), b2, h1);
    h0 = MFMA(LD(5), b3, h0); h1 = MFMA(LD(9), b3, h1);
    b0 = packhalf(h0, 0, true); b1 = packhalf(h0, 8, true);
    b2 = packhalf(h1, 0, true); b3 = packhalf(h1, 8, true);

    // sigma L2 (64->16, NO relu)
    floatx16 hs;
    hs = MFMA(LD(10), b0, z);
    hs = MFMA(LD(11), b1, hs);
    hs = MFMA(LD(12), b2, hs);
    hs = MFMA(LD(13), b3, hs);
    const float sigma = hs[0];                 // row 0 (lanes<32) = sigma
    const short8 bs2 = packhalf(hs, 0, false); // ch0..15 (incl sigma, wt=0)

    // color L0 (19->64: s2 slots + views)
    h0 = MFMA(LD(14), bs2, z);   h1 = MFMA(LD(16), bs2, z);
    h0 = MFMA(LD(15), bv.v, h0); h1 = MFMA(LD(17), bv.v, h1);
    b0 = packhalf(h0, 0, true); b1 = packhalf(h0, 8, true);
    b2 = packhalf(h1, 0, true); b3 = packhalf(h1, 8, true);

    // color L1
    h0 = MFMA(LD(18), b0, z);  h1 = MFMA(LD(22), b0, z);
    h0 = MFMA(LD(19), b1, h0); h1 = MFMA(LD(23), b1, h1);
    h0 = MFMA(LD(20), b2, h0); h1 = MFMA(LD(24), b2, h1);
    h0 = MFMA(LD(21), b3, h0); h1 = MFMA(LD(25), b3, h1);
    b0 = packhalf(h0, 0, true); b1 = packhalf(h0, 8, true);
    b2 = packhalf(h1, 0, true); b3 = packhalf(h1, 8, true);

    // color L2
    h0 = MFMA(LD(26), b0, z);  h1 = MFMA(LD(30), b0, z);
    h0 = MFMA(LD(27), b1, h0); h1 = MFMA(LD(31), b1, h1);
    h0 = MFMA(LD(28), b2, h0); h1 = MFMA(LD(32), b2, h1);
    h0 = MFMA(LD(29), b3, h0); h1 = MFMA(LD(33), b3, h1);
    b0 = packhalf(h0, 0, true); b1 = packhalf(h0, 8, true);
    b2 = packhalf(h1, 0, true); b3 = packhalf(h1, 8, true);

    // color L3 (64->3, NO relu)
    floatx16 hc;
    hc = MFMA(LD(34), b0, z);
    hc = MFMA(LD(35), b1, hc);
    hc = MFMA(LD(36), b2, hc);
    hc = MFMA(LD(37), b3, hc);

    // out[pt] = (color0, color1, color2, sigma) fp32; rows 0..2 are regs 0..2
    // of lanes<32; 16B/point coalesced dwordx4.
    if (lane < 32) {
      float4 o;
      o.x = hc[0]; o.y = hc[1]; o.z = hc[2]; o.w = sigma;
      *(float4*)(out + (size_t)pt * 4) = o;
    }
  }
#undef LD
}

extern "C" void kernel_launch(void* const* d_in, const int* in_sizes, int n_in,
                              void* d_out, int out_size, void* d_ws, size_t ws_size,
                              hipStream_t stream) {
  const float* x = (const float*)d_in[0];
  const float* sw0 = (const float*)d_in[1];
  const float* sw1 = (const float*)d_in[2];
  const float* sw2 = (const float*)d_in[3];
  const float* cw0 = (const float*)d_in[4];
  const float* cw1 = (const float*)d_in[5];
  const float* cw2 = (const float*)d_in[6];
  const float* cw3 = (const float*)d_in[7];
  float* out = (float*)d_out;

  const int npts = in_sizes[0] / 6;         // 1048576
  const int ntiles = npts >> 5;             // 32768
  const int blocks = (ntiles + 4 * TPW - 1) / (4 * TPW);  // 1024 = 4 blocks/CU

  nerf_fused<<<blocks, 256, 0, stream>>>(x, sw0, sw1, sw2, cw0, cw1, cw2, cw3,
                                         out, npts);
}

// Round 5
// 130.355 us; speedup vs baseline: 1.1777x; 1.1002x over previous
//
#include <hip/hip_runtime.h>
#include <stdint.h>

typedef __attribute__((ext_vector_type(8))) short short8;
typedef __attribute__((ext_vector_type(16))) float floatx16;
typedef unsigned int u32;
typedef unsigned short u16;

#define TPW 8  // tiles (of 32 points) per wave; processed 2 at a time

// f32 pair -> packed bf16 (a->low16, b->high16), round-half-up.
// Same 0.5-ulp error bound as RNE (differs only on exact ties); 3 VALU ops.
__device__ __forceinline__ u32 pkhu(float a, float b) {
  return __builtin_amdgcn_perm(__float_as_uint(b) + 0x8000u,
                               __float_as_uint(a) + 0x8000u, 0x07060302u);
}

// RNE f32->bf16 (prologue weights only — keeps weight rounding bit-identical
// to the R3/R4 passing kernels)
__device__ __forceinline__ u16 rtn1(float a) {
  u32 ua = __float_as_uint(a);
  ua += 0x7fffu + ((ua >> 16) & 1u);
  return (u16)(ua >> 16);
}

// channel<->k-slot permutation (involution): swap bits 2 and 3 of low nibble.
// (Algebra HW-verified: R1/R3/R4 passed, absmax 4.8e-3.)
__device__ __forceinline__ int sigperm(int k) {
  int r = k & 15;
  int s = (r & 3) | ((r & 4) << 1) | ((r & 8) >> 1);
  return (k & ~15) | s;
}

// pack 8 consecutive accumulator regs (base=0 or 8) into one B-frag
__device__ __forceinline__ short8 packhalf(const floatx16 a, int base, bool relu) {
  union { u32 u[4]; short8 v; } r;
#pragma unroll
  for (int i = 0; i < 4; ++i) {
    float p = a[base + 2 * i];
    float q = a[base + 2 * i + 1];
    if (relu) { p = fmaxf(p, 0.0f); q = fmaxf(q, 0.0f); }
    r.u[i] = pkhu(p, q);
  }
  return r.v;
}

#define MFMA(A, B, C) __builtin_amdgcn_mfma_f32_32x32x16_bf16(A, B, C, 0, 0, 0)

// Frag-major LDS: 38 frags x 64 lanes x 16B. Frag ids:
//  0..1  s0[rt]          2..9  s1[rt*4+ks]    10..13 s2[ks]
// 14..17 c0[rt*2+ks]    18..25 c1[rt*4+ks]    26..33 c2[rt*4+ks]   34..37 c3[ks]
#define NFRAG 38

__global__ __launch_bounds__(256, 3) void nerf_fused(
    const float* __restrict__ x,
    const float* __restrict__ w_s0, const float* __restrict__ w_s1,
    const float* __restrict__ w_s2, const float* __restrict__ w_c0,
    const float* __restrict__ w_c1, const float* __restrict__ w_c2,
    const float* __restrict__ w_c3,
    float* __restrict__ out, int npts) {
  __shared__ __align__(16) u16 wl[NFRAG * 512];  // 38912 B

  const int lane = threadIdx.x & 63;
  const int wid = threadIdx.x >> 6;
  const int m = lane & 31;   // A-row / B-col (point) index within tile
  const int hi = lane >> 5;  // half-wave -> k-block
  const int kb = hi << 3;

  // ---- prologue: build fragments straight from global, store frag-major ----
  for (int f = wid; f < NFRAG; f += 4) {
    union { u16 e[8]; uint4 q; } u;
    if (f < 2) {                         // s0: 64x3, K padded to 16
      const int row = f * 32 + m;
#pragma unroll
      for (int j = 0; j < 8; ++j) {
        const int k = kb + j;
        u.e[j] = (k < 3) ? rtn1(w_s0[row * 3 + k]) : (u16)0;
      }
    } else if (f < 10) {                 // s1: 64x64
      const int g = f - 2, rt = g >> 2, ks = g & 3;
      const int row = rt * 32 + m;
#pragma unroll
      for (int j = 0; j < 8; ++j)
        u.e[j] = rtn1(w_s1[row * 64 + sigperm(ks * 16 + kb + j)]);
    } else if (f < 14) {                 // s2: 16x64 (rows 16..31 zero)
      const int ks = f - 10;
      const int row = (m < 16) ? m : 0;
#pragma unroll
      for (int j = 0; j < 8; ++j) {
        u16 v = rtn1(w_s2[row * 64 + sigperm(ks * 16 + kb + j)]);
        u.e[j] = (m < 16) ? v : (u16)0;
      }
    } else if (f < 18) {                 // c0: 64x18 (geo slots + view slots)
      const int g = f - 14, rt = g >> 1, ks = g & 1;
      const int row = rt * 32 + m;
#pragma unroll
      for (int j = 0; j < 8; ++j) {
        if (ks == 0) {
          const int c = sigperm(kb + j);   // s2-output channel in this k-slot
          u16 v = rtn1(w_c0[row * 18 + (c + 2)]);
          u.e[j] = (c == 0) ? (u16)0 : v;  // ch0 = sigma -> weight 0
        } else {
          const int kk = kb + j;           // views at k=0..2 of 2nd MFMA
          u16 v = rtn1(w_c0[row * 18 + kk]);
          u.e[j] = (kk < 3) ? v : (u16)0;
        }
      }
    } else if (f < 26) {                 // c1: 64x64
      const int g = f - 18, rt = g >> 2, ks = g & 3;
      const int row = rt * 32 + m;
#pragma unroll
      for (int j = 0; j < 8; ++j)
        u.e[j] = rtn1(w_c1[row * 64 + sigperm(ks * 16 + kb + j)]);
    } else if (f < 34) {                 // c2: 64x64
      const int g = f - 26, rt = g >> 2, ks = g & 3;
      const int row = rt * 32 + m;
#pragma unroll
      for (int j = 0; j < 8; ++j)
        u.e[j] = rtn1(w_c2[row * 64 + sigperm(ks * 16 + kb + j)]);
    } else {                             // c3: 3x64 (rows 3..31 zero)
      const int ks = f - 34;
      const int row = (m < 3) ? m : 0;
#pragma unroll
      for (int j = 0; j < 8; ++j) {
        u16 v = rtn1(w_c3[row * 64 + sigperm(ks * 16 + kb + j)]);
        u.e[j] = (m < 3) ? v : (u16)0;
      }
    }
    *(uint4*)(wl + f * 512 + lane * 8) = u.q;
  }
  __syncthreads();

#define LD(F) (*(const short8*)(wl + (F) * 512 + lane * 8))

  // ---- main loop: 2 independent tiles (64 points) per iteration ----
  const int ntiles = npts >> 5;
  const int wgid = blockIdx.x * 4 + wid;
  const floatx16 z = (floatx16)0.0f;

  for (int t = 0; t < TPW; t += 2) {
    const int tileA = wgid * TPW + t;
    if (tileA >= ntiles) break;
    const int ptA = (tileA << 5) | m;
    const int ptB = ptA + 32;  // tileA+1 (ntiles even, TPW even -> valid)

    const float2* xpA = (const float2*)(x + (size_t)ptA * 6);
    const float2 a0 = xpA[0], a1 = xpA[1], a2 = xpA[2];
    const float2* xpB = (const float2*)(x + (size_t)ptB * 6);
    const float2 c0_ = xpB[0], c1_ = xpB[1], c2_ = xpB[2];

    union { u32 u[4]; short8 v; } bxA, bvA, bxB, bvB;
    bxA.u[0] = hi ? 0u : pkhu(a0.x, a0.y);
    bxA.u[1] = hi ? 0u : pkhu(a1.x, 0.0f);
    bxA.u[2] = 0u; bxA.u[3] = 0u;
    bvA.u[0] = hi ? 0u : pkhu(a1.y, a2.x);
    bvA.u[1] = hi ? 0u : pkhu(a2.y, 0.0f);
    bvA.u[2] = 0u; bvA.u[3] = 0u;
    bxB.u[0] = hi ? 0u : pkhu(c0_.x, c0_.y);
    bxB.u[1] = hi ? 0u : pkhu(c1_.x, 0.0f);
    bxB.u[2] = 0u; bxB.u[3] = 0u;
    bvB.u[0] = hi ? 0u : pkhu(c1_.y, c2_.x);
    bvB.u[1] = hi ? 0u : pkhu(c2_.y, 0.0f);
    bvB.u[2] = 0u; bvB.u[3] = 0u;

    floatx16 hA0, hA1, hB0, hB1;
    short8 w;

    // sigma L0 (K=3 padded)
    w = LD(0); hA0 = MFMA(w, bxA.v, z); hB0 = MFMA(w, bxB.v, z);
    w = LD(1); hA1 = MFMA(w, bxA.v, z); hB1 = MFMA(w, bxB.v, z);
    short8 bA0 = packhalf(hA0, 0, true), bA1 = packhalf(hA0, 8, true);
    short8 bA2 = packhalf(hA1, 0, true), bA3 = packhalf(hA1, 8, true);
    short8 bB0 = packhalf(hB0, 0, true), bB1 = packhalf(hB0, 8, true);
    short8 bB2 = packhalf(hB1, 0, true), bB3 = packhalf(hB1, 8, true);

    // sigma L1 (64->64)
    w = LD(2); hA0 = MFMA(w, bA0, z);   hB0 = MFMA(w, bB0, z);
    w = LD(6); hA1 = MFMA(w, bA0, z);   hB1 = MFMA(w, bB0, z);
    w = LD(3); hA0 = MFMA(w, bA1, hA0); hB0 = MFMA(w, bB1, hB0);
    w = LD(7); hA1 = MFMA(w, bA1, hA1); hB1 = MFMA(w, bB1, hB1);
    w = LD(4); hA0 = MFMA(w, bA2, hA0); hB0 = MFMA(w, bB2, hB0);
    w = LD(8); hA1 = MFMA(w, bA2, hA1); hB1 = MFMA(w, bB2, hB1);
    w = LD(5); hA0 = MFMA(w, bA3, hA0); hB0 = MFMA(w, bB3, hB0);
    w = LD(9); hA1 = MFMA(w, bA3, hA1); hB1 = MFMA(w, bB3, hB1);
    bA0 = packhalf(hA0, 0, true); bA1 = packhalf(hA0, 8, true);
    bA2 = packhalf(hA1, 0, true); bA3 = packhalf(hA1, 8, true);
    bB0 = packhalf(hB0, 0, true); bB1 = packhalf(hB0, 8, true);
    bB2 = packhalf(hB1, 0, true); bB3 = packhalf(hB1, 8, true);

    // sigma L2 (64->16, NO relu)
    floatx16 hsA, hsB;
    w = LD(10); hsA = MFMA(w, bA0, z);   hsB = MFMA(w, bB0, z);
    w = LD(11); hsA = MFMA(w, bA1, hsA); hsB = MFMA(w, bB1, hsB);
    w = LD(12); hsA = MFMA(w, bA2, hsA); hsB = MFMA(w, bB2, hsB);
    w = LD(13); hsA = MFMA(w, bA3, hsA); hsB = MFMA(w, bB3, hsB);
    const float sigmaA = hsA[0], sigmaB = hsB[0];
    const short8 bs2A = packhalf(hsA, 0, false);
    const short8 bs2B = packhalf(hsB, 0, false);

    // color L0 (19->64: s2 slots + views)
    w = LD(14); hA0 = MFMA(w, bs2A, z);    hB0 = MFMA(w, bs2B, z);
    w = LD(16); hA1 = MFMA(w, bs2A, z);    hB1 = MFMA(w, bs2B, z);
    w = LD(15); hA0 = MFMA(w, bvA.v, hA0); hB0 = MFMA(w, bvB.v, hB0);
    w = LD(17); hA1 = MFMA(w, bvA.v, hA1); hB1 = MFMA(w, bvB.v, hB1);
    bA0 = packhalf(hA0, 0, true); bA1 = packhalf(hA0, 8, true);
    bA2 = packhalf(hA1, 0, true); bA3 = packhalf(hA1, 8, true);
    bB0 = packhalf(hB0, 0, true); bB1 = packhalf(hB0, 8, true);
    bB2 = packhalf(hB1, 0, true); bB3 = packhalf(hB1, 8, true);

    // color L1
    w = LD(18); hA0 = MFMA(w, bA0, z);   hB0 = MFMA(w, bB0, z);
    w = LD(22); hA1 = MFMA(w, bA0, z);   hB1 = MFMA(w, bB0, z);
    w = LD(19); hA0 = MFMA(w, bA1, hA0); hB0 = MFMA(w, bB1, hB0);
    w = LD(23); hA1 = MFMA(w, bA1, hA1); hB1 = MFMA(w, bB1, hB1);
    w = LD(20); hA0 = MFMA(w, bA2, hA0); hB0 = MFMA(w, bB2, hB0);
    w = LD(24); hA1 = MFMA(w, bA2, hA1); hB1 = MFMA(w, bB2, hB1);
    w = LD(21); hA0 = MFMA(w, bA3, hA0); hB0 = MFMA(w, bB3, hB0);
    w = LD(25); hA1 = MFMA(w, bA3, hA1); hB1 = MFMA(w, bB3, hB1);
    bA0 = packhalf(hA0, 0, true); bA1 = packhalf(hA0, 8, true);
    bA2 = packhalf(hA1, 0, true); bA3 = packhalf(hA1, 8, true);
    bB0 = packhalf(hB0, 0, true); bB1 = packhalf(hB0, 8, true);
    bB2 = packhalf(hB1, 0, true); bB3 = packhalf(hB1, 8, true);

    // color L2
    w = LD(26); hA0 = MFMA(w, bA0, z);   hB0 = MFMA(w, bB0, z);
    w = LD(30); hA1 = MFMA(w, bA0, z);   hB1 = MFMA(w, bB0, z);
    w = LD(27); hA0 = MFMA(w, bA1, hA0); hB0 = MFMA(w, bB1, hB0);
    w = LD(31); hA1 = MFMA(w, bA1, hA1); hB1 = MFMA(w, bB1, hB1);
    w = LD(28); hA0 = MFMA(w, bA2, hA0); hB0 = MFMA(w, bB2, hB0);
    w = LD(32); hA1 = MFMA(w, bA2, hA1); hB1 = MFMA(w, bB2, hB1);
    w = LD(29); hA0 = MFMA(w, bA3, hA0); hB0 = MFMA(w, bB3, hB0);
    w = LD(33); hA1 = MFMA(w, bA3, hA1); hB1 = MFMA(w, bB3, hB1);
    bA0 = packhalf(hA0, 0, true); bA1 = packhalf(hA0, 8, true);
    bA2 = packhalf(hA1, 0, true); bA3 = packhalf(hA1, 8, true);
    bB0 = packhalf(hB0, 0, true); bB1 = packhalf(hB0, 8, true);
    bB2 = packhalf(hB1, 0, true); bB3 = packhalf(hB1, 8, true);

    // color L3 (64->3, NO relu)
    floatx16 hcA, hcB;
    w = LD(34); hcA = MFMA(w, bA0, z);   hcB = MFMA(w, bB0, z);
    w = LD(35); hcA = MFMA(w, bA1, hcA); hcB = MFMA(w, bB1, hcB);
    w = LD(36); hcA = MFMA(w, bA2, hcA); hcB = MFMA(w, bB2, hcB);
    w = LD(37); hcA = MFMA(w, bA3, hcA); hcB = MFMA(w, bB3, hcB);

    if (lane < 32) {
      float4 oA, oB;
      oA.x = hcA[0]; oA.y = hcA[1]; oA.z = hcA[2]; oA.w = sigmaA;
      oB.x = hcB[0]; oB.y = hcB[1]; oB.z = hcB[2]; oB.w = sigmaB;
      *(float4*)(out + (size_t)ptA * 4) = oA;
      *(float4*)(out + (size_t)ptB * 4) = oB;
    }
  }
#undef LD
}

extern "C" void kernel_launch(void* const* d_in, const int* in_sizes, int n_in,
                              void* d_out, int out_size, void* d_ws, size_t ws_size,
                              hipStream_t stream) {
  const float* x = (const float*)d_in[0];
  const float* sw0 = (const float*)d_in[1];
  const float* sw1 = (const float*)d_in[2];
  const float* sw2 = (const float*)d_in[3];
  const float* cw0 = (const float*)d_in[4];
  const float* cw1 = (const float*)d_in[5];
  const float* cw2 = (const float*)d_in[6];
  const float* cw3 = (const float*)d_in[7];
  float* out = (float*)d_out;

  const int npts = in_sizes[0] / 6;         // 1048576
  const int ntiles = npts >> 5;             // 32768
  const int blocks = (ntiles + 4 * TPW - 1) / (4 * TPW);  // 1024

  nerf_fused<<<blocks, 256, 0, stream>>>(x, sw0, sw1, sw2, cw0, cw1, cw2, cw3,
                                         out, npts);
}